// Round 4
// baseline (6491742.578 us; speedup 1.0000x reference)
//
#include <hip/hip_runtime.h>
#include <stdint.h>

// ============================================================
// MVSEM: memory-augmented attention recurrence.
// B=16 T=512 V=32000 D=512 NM=8 H=8 DH=64 OUT=2048
//
// Round 4: barrier de-contention. Round 3's 6us/barrier was 256 WGs'
// atomic RMWs + polls all hitting ONE 64B MALL line. Now:
//   - per-batch counters padded 256B apart
//   - flag atomic WITHOUT sc1 -> RMW performed in the XCD-local L2
//     (members of a batch share an XCD: bid%8 placement, empirically
//     confirmed by round 3's sc0 data path passing), poll via sc0 loads
//   - poll cap converts a placement-violation deadlock into a fail
//   - 3 independent MFMA accumulator chains in phases A/C
//   - ky/vy row prefetched into registers one step ahead
// ============================================================

typedef __bf16 bf16_t;
typedef __bf16 bf16x8_t __attribute__((ext_vector_type(8)));
typedef __bf16 bf16x4_t __attribute__((ext_vector_type(4)));
typedef float  f32x4_t  __attribute__((ext_vector_type(4)));

#define MFMA16(a, b, c) __builtin_amdgcn_mfma_f32_16x16x32_bf16((a), (b), (c), 0, 0, 0)

// ---- workspace layout (bytes) ----
static const size_t WQKV_H_OFF = 0;                        // bf16 [1536][512]
static const size_t WQKV_L_OFF = 1572864;
static const size_t WO_H_OFF   = 3145728;                  // bf16 [512][512]
static const size_t WO_L_OFF   = 3670016;
static const size_t WP_OFF     = 4194304;                  // bf16 [2048][512]
static const size_t KY_OFF     = 6291456;                  // bf16 [16][512][512]
static const size_t VY_OFF     = 14680064;                 // bf16 [16][512][512]
static const size_t MS_OFF     = 23068672;                 // f32  [16][512][512]
static const size_t SCR_OFF    = 39845888;                 // per-batch 81920 B x 16
static const size_t SCR_BYTES  = (size_t)16 * 81920;
static const size_t CTR_OFF    = SCR_OFF + SCR_BYTES;      // 16 x (64 u32 = 256B)
static const size_t CTR_BYTES  = 16 * 256;
// total ~ 41.2 MB

// ---- sc0 (L1-bypass, L2-coherent) vector loads ----
__device__ __forceinline__ bf16x8_t ldg16(const bf16_t* p) {
  bf16x8_t r;
  asm volatile("global_load_dwordx4 %0, %1, off sc0" : "=v"(r) : "v"(p) : "memory");
  return r;
}
__device__ __forceinline__ f32x4_t ldg16f(const float* p) {
  f32x4_t r;
  asm volatile("global_load_dwordx4 %0, %1, off sc0" : "=v"(r) : "v"(p) : "memory");
  return r;
}
__device__ __forceinline__ void wait_vm0() {
  asm volatile("s_waitcnt vmcnt(0)" ::: "memory");
  __builtin_amdgcn_sched_barrier(0);   // keep consumers after the waitcnt (rule #18)
}

// ------------------------------------------------------------
// f32 -> bf16 (single)
// ------------------------------------------------------------
__global__ __launch_bounds__(256) void cvt_kernel(bf16_t* __restrict__ dst,
                                                  const float* __restrict__ src, int n) {
  int i = (blockIdx.x * 256 + threadIdx.x) * 4;
  if (i >= n) return;
  f32x4_t v = *(const f32x4_t*)(src + i);
  bf16x4_t o;
  o[0] = (bf16_t)v[0]; o[1] = (bf16_t)v[1]; o[2] = (bf16_t)v[2]; o[3] = (bf16_t)v[3];
  *(bf16x4_t*)(dst + i) = o;
}

// f32 -> (hi, lo) bf16 split
__global__ __launch_bounds__(256) void cvt_split_kernel(bf16_t* __restrict__ hi,
                                                        bf16_t* __restrict__ lo,
                                                        const float* __restrict__ src, int n) {
  int i = (blockIdx.x * 256 + threadIdx.x) * 4;
  if (i >= n) return;
  f32x4_t v = *(const f32x4_t*)(src + i);
  bf16x4_t h, l;
#pragma unroll
  for (int j = 0; j < 4; ++j) {
    h[j] = (bf16_t)v[j];
    l[j] = (bf16_t)(v[j] - (float)h[j]);
  }
  *(bf16x4_t*)(hi + i) = h;
  *(bf16x4_t*)(lo + i) = l;
}

// ------------------------------------------------------------
// ky/vy = (mask ? embedding[id] : 0) @ [Wk|Wv]^T + [bk|bv]
// ------------------------------------------------------------
__global__ __launch_bounds__(256) void kyvy_kernel(
    const int* __restrict__ ids,
    const float* __restrict__ emb,
    const bf16_t* __restrict__ Wqkv,
    const float* __restrict__ in_b,
    bf16_t* __restrict__ ky, bf16_t* __restrict__ vy) {
  const int rt = blockIdx.x, cg = blockIdx.y;
  const int wave = threadIdx.x >> 6, lane = threadIdx.x & 63;
  const int l15 = lane & 15, l4 = lane >> 4;

  const int row = rt * 16 + l15;
  const int id = ids[row];
  const float sc = (id != 0) ? 1.f : 0.f;
  const float* esrc = emb + (size_t)id * 512;

  bf16x8_t afrag[16];
#pragma unroll
  for (int k = 0; k < 16; ++k) {
    f32x4_t lo = *(const f32x4_t*)(esrc + k * 32 + l4 * 8);
    f32x4_t hi = *(const f32x4_t*)(esrc + k * 32 + l4 * 8 + 4);
    bf16x8_t a;
#pragma unroll
    for (int j = 0; j < 4; ++j) { a[j] = (bf16_t)(lo[j] * sc); a[j + 4] = (bf16_t)(hi[j] * sc); }
    afrag[k] = a;
  }

#pragma unroll
  for (int dt = 0; dt < 4; ++dt) {
    const int c0 = cg * 256 + wave * 64 + dt * 16;
    const bf16_t* wsrc = Wqkv + (size_t)(512 + c0 + l15) * 512;
    f32x4_t acc = {0.f, 0.f, 0.f, 0.f};
#pragma unroll
    for (int k = 0; k < 16; ++k)
      acc = MFMA16(afrag[k], *(const bf16x8_t*)(wsrc + k * 32 + l4 * 8), acc);
    const int col = c0 + l15;
    const float bias = in_b[512 + col];
#pragma unroll
    for (int r = 0; r < 4; ++r) {
      const int orow = rt * 16 + l4 * 4 + r;
      const float v = acc[r] + bias;
      if (col < 512) ky[(size_t)orow * 512 + col] = (bf16_t)v;
      else           vy[(size_t)orow * 512 + (col - 512)] = (bf16_t)v;
    }
  }
}

// ------------------------------------------------------------
// XCD-local inter-WG barrier (L2-scope atomic, padded counters)
// ------------------------------------------------------------
__device__ __forceinline__ void group_barrier(unsigned int* c, unsigned int target) {
  asm volatile("s_waitcnt vmcnt(0)" ::: "memory");  // my stores are in L2
  __syncthreads();                                   // all waves' stores drained
  if (threadIdx.x == 0) {
    // L2-local atomic RMW (no sc1): performed at the XCD's L2
    asm volatile("global_atomic_add %0, %1, off" :: "v"(c), "v"(1u) : "memory");
    unsigned int v;
    int guard = 0;
    do {
      __builtin_amdgcn_s_sleep(1);
      asm volatile("global_load_dword %0, %1, off sc0\n\t"
                   "s_waitcnt vmcnt(0)"
                   : "=v"(v) : "v"(c) : "memory");
    } while (v < target && ++guard < 65536);
  }
  __syncthreads();
  asm volatile("" ::: "memory");                     // compiler fence for following loads
}

// ------------------------------------------------------------
// The recurrence. grid = 256 (batch = bid&15, member = bid>>4), block = 512.
// ------------------------------------------------------------
__global__ __launch_bounds__(512, 2) void recurrent_kernel(
    const bf16_t* __restrict__ WqkvH, const bf16_t* __restrict__ WqkvL,
    const bf16_t* __restrict__ WoH,   const bf16_t* __restrict__ WoL,
    const float* __restrict__ in_b, const float* __restrict__ ob,
    const float* __restrict__ ln_g, const float* __restrict__ ln_b,
    const float* __restrict__ mem_init,
    const bf16_t* __restrict__ ky, const bf16_t* __restrict__ vy,
    float* __restrict__ MS, bf16_t* __restrict__ scratch, unsigned int* __restrict__ ctr) {
  const int bid = blockIdx.x;
  const int batch = bid & 15;
  const int member = bid >> 4;
  const int tid = threadIdx.x;
  const int wave = tid >> 6;
  const int lane = tid & 63;
  const int l15 = lane & 15, l4 = lane >> 4;

  __shared__ __align__(16) float  Mst[8][520];       // state M (f32)
  __shared__ __align__(16) bf16_t AbfH[16][520];     // M hi (rows 8-15 zero)
  __shared__ __align__(16) bf16_t AbfL[16][520];     // M lo
  __shared__ __align__(16) bf16_t obfH[16][520];     // attn out hi
  __shared__ __align__(16) bf16_t obfL[16][520];     // attn out lo
  __shared__ __align__(16) bf16_t astH[8][16][40];   // softmax probs hi
  __shared__ __align__(16) bf16_t astL[8][16][40];   // softmax probs lo

  bf16_t* qb = scratch + (size_t)batch * 40960;      // [16][512] bf16, rows 8-15 = 0
  bf16_t* kb = qb + 8192;                            // [16][512] row 8 = ky_t, 9-15 = 0
  bf16_t* vT = kb + 8192;                            // [512][32] col 0-7 = vM, 8 = vy_t, 9-31 = 0
  float*  yb = (float*)(vT + 16384);                 // [8][512] f32
  unsigned int* ctrp = ctr + batch * 64;             // 256B-padded counter

  // ---- preload weight B-fragments (hi+lo) into registers ----
  bf16x8_t wfh[16], wfl[16];
  {
    const bf16_t *wsh, *wsl;
    if (wave < 6) {
      wsh = WqkvH + (size_t)(member * 96 + wave * 16 + l15) * 512;
      wsl = WqkvL + (size_t)(member * 96 + wave * 16 + l15) * 512;
    } else {
      wsh = WoH + (size_t)(member * 32 + (wave - 6) * 16 + l15) * 512;
      wsl = WoL + (size_t)(member * 32 + (wave - 6) * 16 + l15) * 512;
    }
#pragma unroll
    for (int k = 0; k < 16; ++k) {
      wfh[k] = *(const bf16x8_t*)(wsh + k * 32 + l4 * 8);
      wfl[k] = *(const bf16x8_t*)(wsl + k * 32 + l4 * 8);
    }
  }
  const float biasA = (wave < 6) ? in_b[member * 96 + wave * 16 + l15]
                                 : ob[member * 32 + (wave - 6) * 16 + l15];
  float g8[8], b8[8];
#pragma unroll
  for (int i = 0; i < 8; ++i) { g8[i] = ln_g[lane * 8 + i]; b8[i] = ln_b[lane * 8 + i]; }

  // ---- ky/vy register prefetch (stager: member 15, waves 6-7) ----
  const bool stager = (member == 15 && wave >= 6);
  const int tt = tid - 384;                           // [0,128) on stager waves
  bf16x4_t kyr = {}, vyr = {};
  if (stager) {
    const bf16_t* kys = ky + (size_t)batch * 512 * 512;
    const bf16_t* vys = vy + (size_t)batch * 512 * 512;
    kyr = *(const bf16x4_t*)(kys + tt * 4);
    vyr = *(const bf16x4_t*)(vys + tt * 4);
  }

  // ---- init LDS ----
  {
    int c = tid;
    for (int r = 0; r < 8; ++r) {
      float v = mem_init[r * 512 + c];
      Mst[r][c] = v;
      bf16_t h = (bf16_t)v;
      AbfH[r][c] = h;
      AbfL[r][c] = (bf16_t)(v - (float)h);
    }
    for (int r = 8; r < 16; ++r) { AbfH[r][c] = (bf16_t)0.f; AbfL[r][c] = (bf16_t)0.f; }
    for (int i = tid; i < 8 * 16 * 40; i += 512) {
      ((bf16_t*)astH)[i] = (bf16_t)0.f;
      ((bf16_t*)astL)[i] = (bf16_t)0.f;
    }
  }
  __syncthreads();

  unsigned int bt = 0;
  for (int t = 0; t < 512; ++t) {
    // ================= Phase A: QKV slices (split precision) =================
    if (wave < 6) {
      const int colbase = member * 96 + wave * 16;
      f32x4_t a0 = {0.f, 0.f, 0.f, 0.f};
      f32x4_t a1 = {0.f, 0.f, 0.f, 0.f};
      f32x4_t a2 = {0.f, 0.f, 0.f, 0.f};
#pragma unroll
      for (int k = 0; k < 16; ++k) {
        bf16x8_t ah = *(const bf16x8_t*)(&AbfH[l15][k * 32 + l4 * 8]);
        bf16x8_t al = *(const bf16x8_t*)(&AbfL[l15][k * 32 + l4 * 8]);
        a0 = MFMA16(ah, wfh[k], a0);
        a1 = MFMA16(al, wfh[k], a1);
        a2 = MFMA16(ah, wfl[k], a2);
      }
      const int col = colbase + l15;
#pragma unroll
      for (int r = 0; r < 4; ++r) {
        const int row = l4 * 4 + r;
        if (row < 8) {
          const float v = a0[r] + a1[r] + a2[r] + biasA;
          if (col < 512)       qb[row * 512 + col] = (bf16_t)v;
          else if (col < 1024) kb[row * 512 + (col - 512)] = (bf16_t)v;
          else                 vT[(col - 1024) * 32 + row] = (bf16_t)v;
        }
      }
    } else if (stager) {
      // store the prefetched y-token K/V row for this step
      const int c = tt * 4;
      *(bf16x4_t*)(kb + 8 * 512 + c) = kyr;
      vT[(c + 0) * 32 + 8] = vyr[0];
      vT[(c + 1) * 32 + 8] = vyr[1];
      vT[(c + 2) * 32 + 8] = vyr[2];
      vT[(c + 3) * 32 + 8] = vyr[3];
    }
    bt += 16;
    group_barrier(ctrp, bt);

    // ================= Phase B: attention (redundant; wave = head) =================
    {
      const int h = wave;
      // issue all exchanged-data loads (sc0: bypass L1, hit shared L2)
      const bf16_t* qp = qb + l15 * 512 + h * 64 + l4 * 8;
      const bf16_t* kp = kb + l15 * 512 + h * 64 + l4 * 8;
      const bf16_t* vp = vT + (h * 64 + l15) * 32 + l4 * 8;
      bf16x8_t qa0 = ldg16(qp);
      bf16x8_t qa1 = ldg16(qp + 32);
      bf16x8_t kf0 = ldg16(kp);
      bf16x8_t kf1 = ldg16(kp + 32);
      bf16x8_t vv0 = ldg16(vp);
      bf16x8_t vv1 = ldg16(vp + 16 * 32);
      bf16x8_t vv2 = ldg16(vp + 32 * 32);
      bf16x8_t vv3 = ldg16(vp + 48 * 32);
      wait_vm0();

      // prefetch next step's ky/vy row (latency hidden under B/C/barrier)
      if (stager) {
        const int tn = (t + 1 < 512) ? t + 1 : 511;
        const bf16_t* kys = ky + ((size_t)batch * 512 + tn) * 512;
        const bf16_t* vys = vy + ((size_t)batch * 512 + tn) * 512;
        kyr = *(const bf16x4_t*)(kys + tt * 4);
        vyr = *(const bf16x4_t*)(vys + tt * 4);
      }

      f32x4_t s = {0.f, 0.f, 0.f, 0.f};
      s = MFMA16(qa0, kf0, s);
      s = MFMA16(qa1, kf1, s);

      float a4[4];
#pragma unroll
      for (int r = 0; r < 4; ++r) {
        float sv = (l15 <= 8) ? s[r] * 0.125f : -1e30f;
        float m = sv;
        m = fmaxf(m, __shfl_xor(m, 1));
        m = fmaxf(m, __shfl_xor(m, 2));
        m = fmaxf(m, __shfl_xor(m, 4));
        m = fmaxf(m, __shfl_xor(m, 8));
        float p = __expf(sv - m);
        float sum = p;
        sum += __shfl_xor(sum, 1);
        sum += __shfl_xor(sum, 2);
        sum += __shfl_xor(sum, 4);
        sum += __shfl_xor(sum, 8);
        a4[r] = p / sum;
      }
#pragma unroll
      for (int r = 0; r < 4; ++r) {
        const float p = a4[r];
        bf16_t ph = (bf16_t)p;
        astH[h][l4 * 4 + r][l15] = ph;
        astL[h][l4 * 4 + r][l15] = (bf16_t)(p - (float)ph);
      }
      __syncthreads();
      bf16x8_t aah = *(const bf16x8_t*)(&astH[h][l15][l4 * 8]);
      bf16x8_t aal = *(const bf16x8_t*)(&astL[h][l15][l4 * 8]);
      {
        f32x4_t z = {0.f, 0.f, 0.f, 0.f};
        f32x4_t o;
        o = MFMA16(aah, vv0, MFMA16(aal, vv0, z));
#pragma unroll
        for (int r = 0; r < 4; ++r) {
          float ov = o[r]; bf16_t oh = (bf16_t)ov;
          obfH[l4 * 4 + r][h * 64 + 0 * 16 + l15] = oh;
          obfL[l4 * 4 + r][h * 64 + 0 * 16 + l15] = (bf16_t)(ov - (float)oh);
        }
        o = MFMA16(aah, vv1, MFMA16(aal, vv1, z));
#pragma unroll
        for (int r = 0; r < 4; ++r) {
          float ov = o[r]; bf16_t oh = (bf16_t)ov;
          obfH[l4 * 4 + r][h * 64 + 1 * 16 + l15] = oh;
          obfL[l4 * 4 + r][h * 64 + 1 * 16 + l15] = (bf16_t)(ov - (float)oh);
        }
        o = MFMA16(aah, vv2, MFMA16(aal, vv2, z));
#pragma unroll
        for (int r = 0; r < 4; ++r) {
          float ov = o[r]; bf16_t oh = (bf16_t)ov;
          obfH[l4 * 4 + r][h * 64 + 2 * 16 + l15] = oh;
          obfL[l4 * 4 + r][h * 64 + 2 * 16 + l15] = (bf16_t)(ov - (float)oh);
        }
        o = MFMA16(aah, vv3, MFMA16(aal, vv3, z));
#pragma unroll
        for (int r = 0; r < 4; ++r) {
          float ov = o[r]; bf16_t oh = (bf16_t)ov;
          obfH[l4 * 4 + r][h * 64 + 3 * 16 + l15] = oh;
          obfL[l4 * 4 + r][h * 64 + 3 * 16 + l15] = (bf16_t)(ov - (float)oh);
        }
      }
    }
    __syncthreads();

    // ================= Phase C: out-proj slice + residual (split) =================
    if (wave >= 6) {
      const int colbase = member * 32 + (wave - 6) * 16;
      f32x4_t a0 = {0.f, 0.f, 0.f, 0.f};
      f32x4_t a1 = {0.f, 0.f, 0.f, 0.f};
      f32x4_t a2 = {0.f, 0.f, 0.f, 0.f};
#pragma unroll
      for (int k = 0; k < 16; ++k) {
        bf16x8_t oh = *(const bf16x8_t*)(&obfH[l15][k * 32 + l4 * 8]);
        bf16x8_t ol = *(const bf16x8_t*)(&obfL[l15][k * 32 + l4 * 8]);
        a0 = MFMA16(oh, wfh[k], a0);
        a1 = MFMA16(ol, wfh[k], a1);
        a2 = MFMA16(oh, wfl[k], a2);
      }
      const int col = colbase + l15;
#pragma unroll
      for (int r = 0; r < 4; ++r) {
        const int row = l4 * 4 + r;
        if (row < 8) yb[row * 512 + col] = a0[r] + a1[r] + a2[r] + biasA + Mst[row][col];
      }
    }
    bt += 16;
    group_barrier(ctrp, bt);

    // ================= Phase D: LayerNorm (redundant; wave = row) =================
    {
      const int r = wave;
      const float* ysrc = yb + r * 512 + lane * 8;
      f32x4_t y0 = ldg16f(ysrc);
      f32x4_t y1 = ldg16f(ysrc + 4);
      wait_vm0();
      float yv[8];
      *(f32x4_t*)(yv)     = y0;
      *(f32x4_t*)(yv + 4) = y1;
      float s1 = 0.f, s2 = 0.f;
#pragma unroll
      for (int i = 0; i < 8; ++i) { s1 += yv[i]; s2 += yv[i] * yv[i]; }
#pragma unroll
      for (int m = 1; m < 64; m <<= 1) { s1 += __shfl_xor(s1, m); s2 += __shfl_xor(s2, m); }
      const float mu = s1 * (1.f / 512.f);
      const float var = s2 * (1.f / 512.f) - mu * mu;
      const float rinv = 1.f / sqrtf(var + 1e-5f);
      float mn[8];
      bf16x8_t mh, ml;
#pragma unroll
      for (int i = 0; i < 8; ++i) {
        mn[i] = (yv[i] - mu) * rinv * g8[i] + b8[i];
        mh[i] = (bf16_t)mn[i];
        ml[i] = (bf16_t)(mn[i] - (float)mh[i]);
      }
      *(f32x4_t*)(&Mst[r][lane * 8])     = *(f32x4_t*)(mn);
      *(f32x4_t*)(&Mst[r][lane * 8 + 4]) = *(f32x4_t*)(mn + 4);
      *(bf16x8_t*)(&AbfH[r][lane * 8]) = mh;
      *(bf16x8_t*)(&AbfL[r][lane * 8]) = ml;
    }
    __syncthreads();
    // summary (mean over the 8 memory rows), written by member 0 only
    {
      const int c = tid;
      float s = 0.f;
#pragma unroll
      for (int r = 0; r < 8; ++r) s += Mst[r][c];
      if (member == 0) MS[((size_t)batch * 512 + t) * 512 + c] = s * 0.125f;
    }
  }
}

// ------------------------------------------------------------
// out = relu(MS @ Wp^T + pb). grid (512, 8), block 256.
// ------------------------------------------------------------
__global__ __launch_bounds__(256) void fproj_kernel(
    const float* __restrict__ MS, const bf16_t* __restrict__ Wp,
    const float* __restrict__ pb, float* __restrict__ out) {
  const int rt = blockIdx.x, cg = blockIdx.y;
  const int wave = threadIdx.x >> 6, lane = threadIdx.x & 63;
  const int l15 = lane & 15, l4 = lane >> 4;

  const float* ms = MS + (size_t)(rt * 16 + l15) * 512;
  bf16x8_t afrag[16];
#pragma unroll
  for (int k = 0; k < 16; ++k) {
    f32x4_t lo = *(const f32x4_t*)(ms + k * 32 + l4 * 8);
    f32x4_t hi = *(const f32x4_t*)(ms + k * 32 + l4 * 8 + 4);
    bf16x8_t a;
#pragma unroll
    for (int j = 0; j < 4; ++j) { a[j] = (bf16_t)lo[j]; a[j + 4] = (bf16_t)hi[j]; }
    afrag[k] = a;
  }

#pragma unroll
  for (int dt = 0; dt < 4; ++dt) {
    const int col0 = cg * 256 + wave * 64 + dt * 16;
    const bf16_t* wsrc = Wp + (size_t)(col0 + l15) * 512;
    f32x4_t acc = {0.f, 0.f, 0.f, 0.f};
#pragma unroll
    for (int k = 0; k < 16; ++k)
      acc = MFMA16(afrag[k], *(const bf16x8_t*)(wsrc + k * 32 + l4 * 8), acc);
    const int col = col0 + l15;
    const float bias = pb[col];
#pragma unroll
    for (int r = 0; r < 4; ++r) {
      const size_t orow = (size_t)rt * 16 + l4 * 4 + r;
      out[orow * 2048 + col] = fmaxf(acc[r] + bias, 0.f);
    }
  }
}

// ------------------------------------------------------------
extern "C" void kernel_launch(void* const* d_in, const int* in_sizes, int n_in,
                              void* d_out, int out_size, void* d_ws, size_t ws_size,
                              hipStream_t stream) {
  (void)in_sizes; (void)n_in; (void)out_size; (void)ws_size;
  const int*   ids  = (const int*)d_in[0];
  const float* embt = (const float*)d_in[1];
  const float* mem0 = (const float*)d_in[2];
  const float* ipw  = (const float*)d_in[3];
  const float* ipb  = (const float*)d_in[4];
  const float* opw  = (const float*)d_in[5];
  const float* opb  = (const float*)d_in[6];
  const float* lng  = (const float*)d_in[7];
  const float* lnb  = (const float*)d_in[8];
  const float* pw   = (const float*)d_in[9];
  const float* pbv  = (const float*)d_in[10];
  float* out = (float*)d_out;
  char* ws = (char*)d_ws;

  bf16_t* WqkvH = (bf16_t*)(ws + WQKV_H_OFF);
  bf16_t* WqkvL = (bf16_t*)(ws + WQKV_L_OFF);
  bf16_t* WoH   = (bf16_t*)(ws + WO_H_OFF);
  bf16_t* WoL   = (bf16_t*)(ws + WO_L_OFF);
  bf16_t* Wp    = (bf16_t*)(ws + WP_OFF);
  bf16_t* ky    = (bf16_t*)(ws + KY_OFF);
  bf16_t* vy    = (bf16_t*)(ws + VY_OFF);
  float*  MS    = (float*)(ws + MS_OFF);
  bf16_t* scr   = (bf16_t*)(ws + SCR_OFF);
  unsigned int* ctr = (unsigned int*)(ws + CTR_OFF);

  // zero exchange buffers + barrier counters (ws is poisoned each call)
  hipMemsetAsync(ws + SCR_OFF, 0, SCR_BYTES + CTR_BYTES, stream);

  cvt_split_kernel<<<768, 256, 0, stream>>>(WqkvH, WqkvL, ipw, 1536 * 512);
  cvt_split_kernel<<<256, 256, 0, stream>>>(WoH, WoL, opw, 512 * 512);
  cvt_kernel<<<1024, 256, 0, stream>>>(Wp, pw, 2048 * 512);

  kyvy_kernel<<<dim3(512, 4), 256, 0, stream>>>(ids, embt, WqkvH, ipb, ky, vy);

  recurrent_kernel<<<256, 512, 0, stream>>>(WqkvH, WqkvL, WoH, WoL, ipb, opb,
                                            lng, lnb, mem0, ky, vy, MS, scr, ctr);

  fproj_kernel<<<dim3(512, 8), 256, 0, stream>>>(MS, Wp, pbv, out);
}

// Round 5
// 5068.069 us; speedup vs baseline: 1280.9105x; 1280.9105x over previous
//
#include <hip/hip_runtime.h>
#include <stdint.h>

// ============================================================
// MVSEM: memory-augmented attention recurrence.
// B=16 T=512 V=32000 D=512 NM=8 H=8 DH=64 OUT=2048
//
// Round 5: revert barrier primitive to the PROVEN agent-scope pair
// (round 4's L2-local atomic + sc0 poll never cohered: every barrier
// spun to the 65536-poll guard = 6.3ms/barrier = the observed 6.49s).
// RMW and poll must share one coherence point: __hip_atomic AGENT
// (sc0 sc1, MALL) for both. Keep round 4's wins:
//   - per-batch counters padded 256B apart (16 RMWs/line, not 256)
//   - 3 independent MFMA accumulator chains in phases A/C
//   - ky/vy row prefetched into registers one step ahead
// Data exchange stays: plain stores -> vmcnt(0) -> barrier -> sc0 loads
// (same-XCD L2, validated rounds 3-4 by correct results).
// ============================================================

typedef __bf16 bf16_t;
typedef __bf16 bf16x8_t __attribute__((ext_vector_type(8)));
typedef __bf16 bf16x4_t __attribute__((ext_vector_type(4)));
typedef float  f32x4_t  __attribute__((ext_vector_type(4)));

#define MFMA16(a, b, c) __builtin_amdgcn_mfma_f32_16x16x32_bf16((a), (b), (c), 0, 0, 0)

// ---- workspace layout (bytes) ----
static const size_t WQKV_H_OFF = 0;                        // bf16 [1536][512]
static const size_t WQKV_L_OFF = 1572864;
static const size_t WO_H_OFF   = 3145728;                  // bf16 [512][512]
static const size_t WO_L_OFF   = 3670016;
static const size_t WP_OFF     = 4194304;                  // bf16 [2048][512]
static const size_t KY_OFF     = 6291456;                  // bf16 [16][512][512]
static const size_t VY_OFF     = 14680064;                 // bf16 [16][512][512]
static const size_t MS_OFF     = 23068672;                 // f32  [16][512][512]
static const size_t SCR_OFF    = 39845888;                 // per-batch 81920 B x 16
static const size_t SCR_BYTES  = (size_t)16 * 81920;
static const size_t CTR_OFF    = SCR_OFF + SCR_BYTES;      // 16 x (64 u32 = 256B)
static const size_t CTR_BYTES  = 16 * 256;
// total ~ 41.2 MB

// ---- sc0 (L1-bypass, L2-coherent) vector loads ----
__device__ __forceinline__ bf16x8_t ldg16(const bf16_t* p) {
  bf16x8_t r;
  asm volatile("global_load_dwordx4 %0, %1, off sc0" : "=v"(r) : "v"(p) : "memory");
  return r;
}
__device__ __forceinline__ f32x4_t ldg16f(const float* p) {
  f32x4_t r;
  asm volatile("global_load_dwordx4 %0, %1, off sc0" : "=v"(r) : "v"(p) : "memory");
  return r;
}
__device__ __forceinline__ void wait_vm0() {
  asm volatile("s_waitcnt vmcnt(0)" ::: "memory");
  __builtin_amdgcn_sched_barrier(0);   // keep consumers after the waitcnt (rule #18)
}

// ------------------------------------------------------------
// f32 -> bf16 (single)
// ------------------------------------------------------------
__global__ __launch_bounds__(256) void cvt_kernel(bf16_t* __restrict__ dst,
                                                  const float* __restrict__ src, int n) {
  int i = (blockIdx.x * 256 + threadIdx.x) * 4;
  if (i >= n) return;
  f32x4_t v = *(const f32x4_t*)(src + i);
  bf16x4_t o;
  o[0] = (bf16_t)v[0]; o[1] = (bf16_t)v[1]; o[2] = (bf16_t)v[2]; o[3] = (bf16_t)v[3];
  *(bf16x4_t*)(dst + i) = o;
}

// f32 -> (hi, lo) bf16 split
__global__ __launch_bounds__(256) void cvt_split_kernel(bf16_t* __restrict__ hi,
                                                        bf16_t* __restrict__ lo,
                                                        const float* __restrict__ src, int n) {
  int i = (blockIdx.x * 256 + threadIdx.x) * 4;
  if (i >= n) return;
  f32x4_t v = *(const f32x4_t*)(src + i);
  bf16x4_t h, l;
#pragma unroll
  for (int j = 0; j < 4; ++j) {
    h[j] = (bf16_t)v[j];
    l[j] = (bf16_t)(v[j] - (float)h[j]);
  }
  *(bf16x4_t*)(hi + i) = h;
  *(bf16x4_t*)(lo + i) = l;
}

// ------------------------------------------------------------
// ky/vy = (mask ? embedding[id] : 0) @ [Wk|Wv]^T + [bk|bv]
// ------------------------------------------------------------
__global__ __launch_bounds__(256) void kyvy_kernel(
    const int* __restrict__ ids,
    const float* __restrict__ emb,
    const bf16_t* __restrict__ Wqkv,
    const float* __restrict__ in_b,
    bf16_t* __restrict__ ky, bf16_t* __restrict__ vy) {
  const int rt = blockIdx.x, cg = blockIdx.y;
  const int wave = threadIdx.x >> 6, lane = threadIdx.x & 63;
  const int l15 = lane & 15, l4 = lane >> 4;

  const int row = rt * 16 + l15;
  const int id = ids[row];
  const float sc = (id != 0) ? 1.f : 0.f;
  const float* esrc = emb + (size_t)id * 512;

  bf16x8_t afrag[16];
#pragma unroll
  for (int k = 0; k < 16; ++k) {
    f32x4_t lo = *(const f32x4_t*)(esrc + k * 32 + l4 * 8);
    f32x4_t hi = *(const f32x4_t*)(esrc + k * 32 + l4 * 8 + 4);
    bf16x8_t a;
#pragma unroll
    for (int j = 0; j < 4; ++j) { a[j] = (bf16_t)(lo[j] * sc); a[j + 4] = (bf16_t)(hi[j] * sc); }
    afrag[k] = a;
  }

#pragma unroll
  for (int dt = 0; dt < 4; ++dt) {
    const int c0 = cg * 256 + wave * 64 + dt * 16;
    const bf16_t* wsrc = Wqkv + (size_t)(512 + c0 + l15) * 512;
    f32x4_t acc = {0.f, 0.f, 0.f, 0.f};
#pragma unroll
    for (int k = 0; k < 16; ++k)
      acc = MFMA16(afrag[k], *(const bf16x8_t*)(wsrc + k * 32 + l4 * 8), acc);
    const int col = c0 + l15;
    const float bias = in_b[512 + col];
#pragma unroll
    for (int r = 0; r < 4; ++r) {
      const int orow = rt * 16 + l4 * 4 + r;
      const float v = acc[r] + bias;
      if (col < 512) ky[(size_t)orow * 512 + col] = (bf16_t)v;
      else           vy[(size_t)orow * 512 + (col - 512)] = (bf16_t)v;
    }
  }
}

// ------------------------------------------------------------
// inter-WG barrier: agent-scope atomic add + agent-scope poll (both at
// the MALL -> one coherence point; proven in round 3). Padded counters.
// ------------------------------------------------------------
__device__ __forceinline__ void group_barrier(unsigned int* c, unsigned int target) {
  asm volatile("s_waitcnt vmcnt(0)" ::: "memory");  // my stores are in L2
  __syncthreads();                                   // all waves' stores drained
  if (threadIdx.x == 0) {
    __hip_atomic_fetch_add(c, 1u, __ATOMIC_RELAXED, __HIP_MEMORY_SCOPE_AGENT);
    int guard = 0;
    while (__hip_atomic_load(c, __ATOMIC_RELAXED, __HIP_MEMORY_SCOPE_AGENT) < target &&
           ++guard < (1 << 18))
      __builtin_amdgcn_s_sleep(1);
  }
  __syncthreads();
  asm volatile("" ::: "memory");                     // compiler fence for following loads
}

// ------------------------------------------------------------
// The recurrence. grid = 256 (batch = bid&15, member = bid>>4), block = 512.
// ------------------------------------------------------------
__global__ __launch_bounds__(512, 2) void recurrent_kernel(
    const bf16_t* __restrict__ WqkvH, const bf16_t* __restrict__ WqkvL,
    const bf16_t* __restrict__ WoH,   const bf16_t* __restrict__ WoL,
    const float* __restrict__ in_b, const float* __restrict__ ob,
    const float* __restrict__ ln_g, const float* __restrict__ ln_b,
    const float* __restrict__ mem_init,
    const bf16_t* __restrict__ ky, const bf16_t* __restrict__ vy,
    float* __restrict__ MS, bf16_t* __restrict__ scratch, unsigned int* __restrict__ ctr) {
  const int bid = blockIdx.x;
  const int batch = bid & 15;
  const int member = bid >> 4;
  const int tid = threadIdx.x;
  const int wave = tid >> 6;
  const int lane = tid & 63;
  const int l15 = lane & 15, l4 = lane >> 4;

  __shared__ __align__(16) float  Mst[8][520];       // state M (f32)
  __shared__ __align__(16) bf16_t AbfH[16][520];     // M hi (rows 8-15 zero)
  __shared__ __align__(16) bf16_t AbfL[16][520];     // M lo
  __shared__ __align__(16) bf16_t obfH[16][520];     // attn out hi
  __shared__ __align__(16) bf16_t obfL[16][520];     // attn out lo
  __shared__ __align__(16) bf16_t astH[8][16][40];   // softmax probs hi
  __shared__ __align__(16) bf16_t astL[8][16][40];   // softmax probs lo

  bf16_t* qb = scratch + (size_t)batch * 40960;      // [16][512] bf16, rows 8-15 = 0
  bf16_t* kb = qb + 8192;                            // [16][512] row 8 = ky_t, 9-15 = 0
  bf16_t* vT = kb + 8192;                            // [512][32] col 0-7 = vM, 8 = vy_t, 9-31 = 0
  float*  yb = (float*)(vT + 16384);                 // [8][512] f32
  unsigned int* ctrp = ctr + batch * 64;             // 256B-padded counter

  // ---- preload weight B-fragments (hi+lo) into registers ----
  bf16x8_t wfh[16], wfl[16];
  {
    const bf16_t *wsh, *wsl;
    if (wave < 6) {
      wsh = WqkvH + (size_t)(member * 96 + wave * 16 + l15) * 512;
      wsl = WqkvL + (size_t)(member * 96 + wave * 16 + l15) * 512;
    } else {
      wsh = WoH + (size_t)(member * 32 + (wave - 6) * 16 + l15) * 512;
      wsl = WoL + (size_t)(member * 32 + (wave - 6) * 16 + l15) * 512;
    }
#pragma unroll
    for (int k = 0; k < 16; ++k) {
      wfh[k] = *(const bf16x8_t*)(wsh + k * 32 + l4 * 8);
      wfl[k] = *(const bf16x8_t*)(wsl + k * 32 + l4 * 8);
    }
  }
  const float biasA = (wave < 6) ? in_b[member * 96 + wave * 16 + l15]
                                 : ob[member * 32 + (wave - 6) * 16 + l15];
  float g8[8], b8[8];
#pragma unroll
  for (int i = 0; i < 8; ++i) { g8[i] = ln_g[lane * 8 + i]; b8[i] = ln_b[lane * 8 + i]; }

  // ---- ky/vy register prefetch (stager: member 15, waves 6-7) ----
  const bool stager = (member == 15 && wave >= 6);
  const int tt = tid - 384;                           // [0,128) on stager waves
  bf16x4_t kyr = {}, vyr = {};
  if (stager) {
    const bf16_t* kys = ky + (size_t)batch * 512 * 512;
    const bf16_t* vys = vy + (size_t)batch * 512 * 512;
    kyr = *(const bf16x4_t*)(kys + tt * 4);
    vyr = *(const bf16x4_t*)(vys + tt * 4);
  }

  // ---- init LDS ----
  {
    int c = tid;
    for (int r = 0; r < 8; ++r) {
      float v = mem_init[r * 512 + c];
      Mst[r][c] = v;
      bf16_t h = (bf16_t)v;
      AbfH[r][c] = h;
      AbfL[r][c] = (bf16_t)(v - (float)h);
    }
    for (int r = 8; r < 16; ++r) { AbfH[r][c] = (bf16_t)0.f; AbfL[r][c] = (bf16_t)0.f; }
    for (int i = tid; i < 8 * 16 * 40; i += 512) {
      ((bf16_t*)astH)[i] = (bf16_t)0.f;
      ((bf16_t*)astL)[i] = (bf16_t)0.f;
    }
  }
  __syncthreads();

  unsigned int bt = 0;
  for (int t = 0; t < 512; ++t) {
    // ================= Phase A: QKV slices (split precision) =================
    if (wave < 6) {
      const int colbase = member * 96 + wave * 16;
      f32x4_t a0 = {0.f, 0.f, 0.f, 0.f};
      f32x4_t a1 = {0.f, 0.f, 0.f, 0.f};
      f32x4_t a2 = {0.f, 0.f, 0.f, 0.f};
#pragma unroll
      for (int k = 0; k < 16; ++k) {
        bf16x8_t ah = *(const bf16x8_t*)(&AbfH[l15][k * 32 + l4 * 8]);
        bf16x8_t al = *(const bf16x8_t*)(&AbfL[l15][k * 32 + l4 * 8]);
        a0 = MFMA16(ah, wfh[k], a0);
        a1 = MFMA16(al, wfh[k], a1);
        a2 = MFMA16(ah, wfl[k], a2);
      }
      const int col = colbase + l15;
#pragma unroll
      for (int r = 0; r < 4; ++r) {
        const int row = l4 * 4 + r;
        if (row < 8) {
          const float v = a0[r] + a1[r] + a2[r] + biasA;
          if (col < 512)       qb[row * 512 + col] = (bf16_t)v;
          else if (col < 1024) kb[row * 512 + (col - 512)] = (bf16_t)v;
          else                 vT[(col - 1024) * 32 + row] = (bf16_t)v;
        }
      }
    } else if (stager) {
      // store the prefetched y-token K/V row for this step
      const int c = tt * 4;
      *(bf16x4_t*)(kb + 8 * 512 + c) = kyr;
      vT[(c + 0) * 32 + 8] = vyr[0];
      vT[(c + 1) * 32 + 8] = vyr[1];
      vT[(c + 2) * 32 + 8] = vyr[2];
      vT[(c + 3) * 32 + 8] = vyr[3];
    }
    bt += 16;
    group_barrier(ctrp, bt);

    // ================= Phase B: attention (redundant; wave = head) =================
    {
      const int h = wave;
      // issue all exchanged-data loads (sc0: bypass L1, hit shared L2)
      const bf16_t* qp = qb + l15 * 512 + h * 64 + l4 * 8;
      const bf16_t* kp = kb + l15 * 512 + h * 64 + l4 * 8;
      const bf16_t* vp = vT + (h * 64 + l15) * 32 + l4 * 8;
      bf16x8_t qa0 = ldg16(qp);
      bf16x8_t qa1 = ldg16(qp + 32);
      bf16x8_t kf0 = ldg16(kp);
      bf16x8_t kf1 = ldg16(kp + 32);
      bf16x8_t vv0 = ldg16(vp);
      bf16x8_t vv1 = ldg16(vp + 16 * 32);
      bf16x8_t vv2 = ldg16(vp + 32 * 32);
      bf16x8_t vv3 = ldg16(vp + 48 * 32);
      wait_vm0();

      // prefetch next step's ky/vy row (latency hidden under B/C/barrier)
      if (stager) {
        const int tn = (t + 1 < 512) ? t + 1 : 511;
        const bf16_t* kys = ky + ((size_t)batch * 512 + tn) * 512;
        const bf16_t* vys = vy + ((size_t)batch * 512 + tn) * 512;
        kyr = *(const bf16x4_t*)(kys + tt * 4);
        vyr = *(const bf16x4_t*)(vys + tt * 4);
      }

      f32x4_t s = {0.f, 0.f, 0.f, 0.f};
      s = MFMA16(qa0, kf0, s);
      s = MFMA16(qa1, kf1, s);

      float a4[4];
#pragma unroll
      for (int r = 0; r < 4; ++r) {
        float sv = (l15 <= 8) ? s[r] * 0.125f : -1e30f;
        float m = sv;
        m = fmaxf(m, __shfl_xor(m, 1));
        m = fmaxf(m, __shfl_xor(m, 2));
        m = fmaxf(m, __shfl_xor(m, 4));
        m = fmaxf(m, __shfl_xor(m, 8));
        float p = __expf(sv - m);
        float sum = p;
        sum += __shfl_xor(sum, 1);
        sum += __shfl_xor(sum, 2);
        sum += __shfl_xor(sum, 4);
        sum += __shfl_xor(sum, 8);
        a4[r] = p / sum;
      }
#pragma unroll
      for (int r = 0; r < 4; ++r) {
        const float p = a4[r];
        bf16_t ph = (bf16_t)p;
        astH[h][l4 * 4 + r][l15] = ph;
        astL[h][l4 * 4 + r][l15] = (bf16_t)(p - (float)ph);
      }
      __syncthreads();
      bf16x8_t aah = *(const bf16x8_t*)(&astH[h][l15][l4 * 8]);
      bf16x8_t aal = *(const bf16x8_t*)(&astL[h][l15][l4 * 8]);
      {
        f32x4_t z = {0.f, 0.f, 0.f, 0.f};
        f32x4_t o;
        o = MFMA16(aah, vv0, MFMA16(aal, vv0, z));
#pragma unroll
        for (int r = 0; r < 4; ++r) {
          float ov = o[r]; bf16_t oh = (bf16_t)ov;
          obfH[l4 * 4 + r][h * 64 + 0 * 16 + l15] = oh;
          obfL[l4 * 4 + r][h * 64 + 0 * 16 + l15] = (bf16_t)(ov - (float)oh);
        }
        o = MFMA16(aah, vv1, MFMA16(aal, vv1, z));
#pragma unroll
        for (int r = 0; r < 4; ++r) {
          float ov = o[r]; bf16_t oh = (bf16_t)ov;
          obfH[l4 * 4 + r][h * 64 + 1 * 16 + l15] = oh;
          obfL[l4 * 4 + r][h * 64 + 1 * 16 + l15] = (bf16_t)(ov - (float)oh);
        }
        o = MFMA16(aah, vv2, MFMA16(aal, vv2, z));
#pragma unroll
        for (int r = 0; r < 4; ++r) {
          float ov = o[r]; bf16_t oh = (bf16_t)ov;
          obfH[l4 * 4 + r][h * 64 + 2 * 16 + l15] = oh;
          obfL[l4 * 4 + r][h * 64 + 2 * 16 + l15] = (bf16_t)(ov - (float)oh);
        }
        o = MFMA16(aah, vv3, MFMA16(aal, vv3, z));
#pragma unroll
        for (int r = 0; r < 4; ++r) {
          float ov = o[r]; bf16_t oh = (bf16_t)ov;
          obfH[l4 * 4 + r][h * 64 + 3 * 16 + l15] = oh;
          obfL[l4 * 4 + r][h * 64 + 3 * 16 + l15] = (bf16_t)(ov - (float)oh);
        }
      }
    }
    __syncthreads();

    // ================= Phase C: out-proj slice + residual (split) =================
    if (wave >= 6) {
      const int colbase = member * 32 + (wave - 6) * 16;
      f32x4_t a0 = {0.f, 0.f, 0.f, 0.f};
      f32x4_t a1 = {0.f, 0.f, 0.f, 0.f};
      f32x4_t a2 = {0.f, 0.f, 0.f, 0.f};
#pragma unroll
      for (int k = 0; k < 16; ++k) {
        bf16x8_t oh = *(const bf16x8_t*)(&obfH[l15][k * 32 + l4 * 8]);
        bf16x8_t ol = *(const bf16x8_t*)(&obfL[l15][k * 32 + l4 * 8]);
        a0 = MFMA16(oh, wfh[k], a0);
        a1 = MFMA16(ol, wfh[k], a1);
        a2 = MFMA16(oh, wfl[k], a2);
      }
      const int col = colbase + l15;
#pragma unroll
      for (int r = 0; r < 4; ++r) {
        const int row = l4 * 4 + r;
        if (row < 8) yb[row * 512 + col] = a0[r] + a1[r] + a2[r] + biasA + Mst[row][col];
      }
    }
    bt += 16;
    group_barrier(ctrp, bt);

    // ================= Phase D: LayerNorm (redundant; wave = row) =================
    {
      const int r = wave;
      const float* ysrc = yb + r * 512 + lane * 8;
      f32x4_t y0 = ldg16f(ysrc);
      f32x4_t y1 = ldg16f(ysrc + 4);
      wait_vm0();
      float yv[8];
      *(f32x4_t*)(yv)     = y0;
      *(f32x4_t*)(yv + 4) = y1;
      float s1 = 0.f, s2 = 0.f;
#pragma unroll
      for (int i = 0; i < 8; ++i) { s1 += yv[i]; s2 += yv[i] * yv[i]; }
#pragma unroll
      for (int m = 1; m < 64; m <<= 1) { s1 += __shfl_xor(s1, m); s2 += __shfl_xor(s2, m); }
      const float mu = s1 * (1.f / 512.f);
      const float var = s2 * (1.f / 512.f) - mu * mu;
      const float rinv = 1.f / sqrtf(var + 1e-5f);
      float mn[8];
      bf16x8_t mh, ml;
#pragma unroll
      for (int i = 0; i < 8; ++i) {
        mn[i] = (yv[i] - mu) * rinv * g8[i] + b8[i];
        mh[i] = (bf16_t)mn[i];
        ml[i] = (bf16_t)(mn[i] - (float)mh[i]);
      }
      *(f32x4_t*)(&Mst[r][lane * 8])     = *(f32x4_t*)(mn);
      *(f32x4_t*)(&Mst[r][lane * 8 + 4]) = *(f32x4_t*)(mn + 4);
      *(bf16x8_t*)(&AbfH[r][lane * 8]) = mh;
      *(bf16x8_t*)(&AbfL[r][lane * 8]) = ml;
    }
    __syncthreads();
    // summary (mean over the 8 memory rows), written by member 0 only
    {
      const int c = tid;
      float s = 0.f;
#pragma unroll
      for (int r = 0; r < 8; ++r) s += Mst[r][c];
      if (member == 0) MS[((size_t)batch * 512 + t) * 512 + c] = s * 0.125f;
    }
  }
}

// ------------------------------------------------------------
// out = relu(MS @ Wp^T + pb). grid (512, 8), block 256.
// ------------------------------------------------------------
__global__ __launch_bounds__(256) void fproj_kernel(
    const float* __restrict__ MS, const bf16_t* __restrict__ Wp,
    const float* __restrict__ pb, float* __restrict__ out) {
  const int rt = blockIdx.x, cg = blockIdx.y;
  const int wave = threadIdx.x >> 6, lane = threadIdx.x & 63;
  const int l15 = lane & 15, l4 = lane >> 4;

  const float* ms = MS + (size_t)(rt * 16 + l15) * 512;
  bf16x8_t afrag[16];
#pragma unroll
  for (int k = 0; k < 16; ++k) {
    f32x4_t lo = *(const f32x4_t*)(ms + k * 32 + l4 * 8);
    f32x4_t hi = *(const f32x4_t*)(ms + k * 32 + l4 * 8 + 4);
    bf16x8_t a;
#pragma unroll
    for (int j = 0; j < 4; ++j) { a[j] = (bf16_t)lo[j]; a[j + 4] = (bf16_t)hi[j]; }
    afrag[k] = a;
  }

#pragma unroll
  for (int dt = 0; dt < 4; ++dt) {
    const int col0 = cg * 256 + wave * 64 + dt * 16;
    const bf16_t* wsrc = Wp + (size_t)(col0 + l15) * 512;
    f32x4_t acc = {0.f, 0.f, 0.f, 0.f};
#pragma unroll
    for (int k = 0; k < 16; ++k)
      acc = MFMA16(afrag[k], *(const bf16x8_t*)(wsrc + k * 32 + l4 * 8), acc);
    const int col = col0 + l15;
    const float bias = pb[col];
#pragma unroll
    for (int r = 0; r < 4; ++r) {
      const size_t orow = (size_t)rt * 16 + l4 * 4 + r;
      out[orow * 2048 + col] = fmaxf(acc[r] + bias, 0.f);
    }
  }
}

// ------------------------------------------------------------
extern "C" void kernel_launch(void* const* d_in, const int* in_sizes, int n_in,
                              void* d_out, int out_size, void* d_ws, size_t ws_size,
                              hipStream_t stream) {
  (void)in_sizes; (void)n_in; (void)out_size; (void)ws_size;
  const int*   ids  = (const int*)d_in[0];
  const float* embt = (const float*)d_in[1];
  const float* mem0 = (const float*)d_in[2];
  const float* ipw  = (const float*)d_in[3];
  const float* ipb  = (const float*)d_in[4];
  const float* opw  = (const float*)d_in[5];
  const float* opb  = (const float*)d_in[6];
  const float* lng  = (const float*)d_in[7];
  const float* lnb  = (const float*)d_in[8];
  const float* pw   = (const float*)d_in[9];
  const float* pbv  = (const float*)d_in[10];
  float* out = (float*)d_out;
  char* ws = (char*)d_ws;

  bf16_t* WqkvH = (bf16_t*)(ws + WQKV_H_OFF);
  bf16_t* WqkvL = (bf16_t*)(ws + WQKV_L_OFF);
  bf16_t* WoH   = (bf16_t*)(ws + WO_H_OFF);
  bf16_t* WoL   = (bf16_t*)(ws + WO_L_OFF);
  bf16_t* Wp    = (bf16_t*)(ws + WP_OFF);
  bf16_t* ky    = (bf16_t*)(ws + KY_OFF);
  bf16_t* vy    = (bf16_t*)(ws + VY_OFF);
  float*  MS    = (float*)(ws + MS_OFF);
  bf16_t* scr   = (bf16_t*)(ws + SCR_OFF);
  unsigned int* ctr = (unsigned int*)(ws + CTR_OFF);

  // zero exchange buffers + barrier counters (ws is poisoned each call)
  hipMemsetAsync(ws + SCR_OFF, 0, SCR_BYTES + CTR_BYTES, stream);

  cvt_split_kernel<<<768, 256, 0, stream>>>(WqkvH, WqkvL, ipw, 1536 * 512);
  cvt_split_kernel<<<256, 256, 0, stream>>>(WoH, WoL, opw, 512 * 512);
  cvt_kernel<<<1024, 256, 0, stream>>>(Wp, pw, 2048 * 512);

  kyvy_kernel<<<dim3(512, 4), 256, 0, stream>>>(ids, embt, WqkvH, ipb, ky, vy);

  recurrent_kernel<<<256, 512, 0, stream>>>(WqkvH, WqkvL, WoH, WoL, ipb, opb,
                                            lng, lnb, mem0, ky, vy, MS, scr, ctr);

  fproj_kernel<<<dim3(512, 8), 256, 0, stream>>>(MS, Wp, pbv, out);
}

// Round 7
// 4947.219 us; speedup vs baseline: 1312.2003x; 1.0244x over previous
//
#include <hip/hip_runtime.h>
#include <stdint.h>

// ============================================================
// MVSEM: memory-augmented attention recurrence.
// B=16 T=512 V=32000 D=512 NM=8 H=8 DH=64 OUT=2048
//
// Round 7 == Round 6 resubmitted (round 6 hit GPUAcquisitionTimeout;
// kernel never executed):
//   1. Store-flag barrier: each member STORES a monotonic step-tag to its
//      own 64B-padded flag (no RMW serialization at the MALL); each WG
//      polls all 16 flags with 16 parallel lane-loads (1 RTT). Tags
//      2t+1 / 2t+2 are monotonic -> no reset, rush-safe. Both sides use
//      relaxed AGENT atomics (sc0 sc1, MALL) = the proven coherence path.
//   2. __launch_bounds__(512,1): the old (512,2) capped VGPRs at 128 --
//      pointless (104KB LDS already limits to 1 block/CU) and too small
//      for the 128-VGPR weight set to be register-resident.
// Data exchange unchanged: plain stores -> vmcnt(0) -> barrier -> sc0
// loads (same-XCD L2, validated rounds 3-5).
// ============================================================

typedef __bf16 bf16_t;
typedef __bf16 bf16x8_t __attribute__((ext_vector_type(8)));
typedef __bf16 bf16x4_t __attribute__((ext_vector_type(4)));
typedef float  f32x4_t  __attribute__((ext_vector_type(4)));

#define MFMA16(a, b, c) __builtin_amdgcn_mfma_f32_16x16x32_bf16((a), (b), (c), 0, 0, 0)

// ---- workspace layout (bytes) ----
static const size_t WQKV_H_OFF = 0;                        // bf16 [1536][512]
static const size_t WQKV_L_OFF = 1572864;
static const size_t WO_H_OFF   = 3145728;                  // bf16 [512][512]
static const size_t WO_L_OFF   = 3670016;
static const size_t WP_OFF     = 4194304;                  // bf16 [2048][512]
static const size_t KY_OFF     = 6291456;                  // bf16 [16][512][512]
static const size_t VY_OFF     = 14680064;                 // bf16 [16][512][512]
static const size_t MS_OFF     = 23068672;                 // f32  [16][512][512]
static const size_t SCR_OFF    = 39845888;                 // per-batch 81920 B x 16
static const size_t SCR_BYTES  = (size_t)16 * 81920;
static const size_t CTR_OFF    = SCR_OFF + SCR_BYTES;      // flags: 16 batches x 16 members x 64B
static const size_t CTR_BYTES  = 16 * 16 * 64;             // 16 KB
// total ~ 41.2 MB

// ---- sc0 (L1-bypass, L2-coherent) vector loads ----
__device__ __forceinline__ bf16x8_t ldg16(const bf16_t* p) {
  bf16x8_t r;
  asm volatile("global_load_dwordx4 %0, %1, off sc0" : "=v"(r) : "v"(p) : "memory");
  return r;
}
__device__ __forceinline__ f32x4_t ldg16f(const float* p) {
  f32x4_t r;
  asm volatile("global_load_dwordx4 %0, %1, off sc0" : "=v"(r) : "v"(p) : "memory");
  return r;
}
__device__ __forceinline__ void wait_vm0() {
  asm volatile("s_waitcnt vmcnt(0)" ::: "memory");
  __builtin_amdgcn_sched_barrier(0);   // keep consumers after the waitcnt (rule #18)
}

// ------------------------------------------------------------
// f32 -> bf16 (single)
// ------------------------------------------------------------
__global__ __launch_bounds__(256) void cvt_kernel(bf16_t* __restrict__ dst,
                                                  const float* __restrict__ src, int n) {
  int i = (blockIdx.x * 256 + threadIdx.x) * 4;
  if (i >= n) return;
  f32x4_t v = *(const f32x4_t*)(src + i);
  bf16x4_t o;
  o[0] = (bf16_t)v[0]; o[1] = (bf16_t)v[1]; o[2] = (bf16_t)v[2]; o[3] = (bf16_t)v[3];
  *(bf16x4_t*)(dst + i) = o;
}

// f32 -> (hi, lo) bf16 split
__global__ __launch_bounds__(256) void cvt_split_kernel(bf16_t* __restrict__ hi,
                                                        bf16_t* __restrict__ lo,
                                                        const float* __restrict__ src, int n) {
  int i = (blockIdx.x * 256 + threadIdx.x) * 4;
  if (i >= n) return;
  f32x4_t v = *(const f32x4_t*)(src + i);
  bf16x4_t h, l;
#pragma unroll
  for (int j = 0; j < 4; ++j) {
    h[j] = (bf16_t)v[j];
    l[j] = (bf16_t)(v[j] - (float)h[j]);
  }
  *(bf16x4_t*)(hi + i) = h;
  *(bf16x4_t*)(lo + i) = l;
}

// ------------------------------------------------------------
// ky/vy = (mask ? embedding[id] : 0) @ [Wk|Wv]^T + [bk|bv]
// ------------------------------------------------------------
__global__ __launch_bounds__(256) void kyvy_kernel(
    const int* __restrict__ ids,
    const float* __restrict__ emb,
    const bf16_t* __restrict__ Wqkv,
    const float* __restrict__ in_b,
    bf16_t* __restrict__ ky, bf16_t* __restrict__ vy) {
  const int rt = blockIdx.x, cg = blockIdx.y;
  const int wave = threadIdx.x >> 6, lane = threadIdx.x & 63;
  const int l15 = lane & 15, l4 = lane >> 4;

  const int row = rt * 16 + l15;
  const int id = ids[row];
  const float sc = (id != 0) ? 1.f : 0.f;
  const float* esrc = emb + (size_t)id * 512;

  bf16x8_t afrag[16];
#pragma unroll
  for (int k = 0; k < 16; ++k) {
    f32x4_t lo = *(const f32x4_t*)(esrc + k * 32 + l4 * 8);
    f32x4_t hi = *(const f32x4_t*)(esrc + k * 32 + l4 * 8 + 4);
    bf16x8_t a;
#pragma unroll
    for (int j = 0; j < 4; ++j) { a[j] = (bf16_t)(lo[j] * sc); a[j + 4] = (bf16_t)(hi[j] * sc); }
    afrag[k] = a;
  }

#pragma unroll
  for (int dt = 0; dt < 4; ++dt) {
    const int c0 = cg * 256 + wave * 64 + dt * 16;
    const bf16_t* wsrc = Wqkv + (size_t)(512 + c0 + l15) * 512;
    f32x4_t acc = {0.f, 0.f, 0.f, 0.f};
#pragma unroll
    for (int k = 0; k < 16; ++k)
      acc = MFMA16(afrag[k], *(const bf16x8_t*)(wsrc + k * 32 + l4 * 8), acc);
    const int col = c0 + l15;
    const float bias = in_b[512 + col];
#pragma unroll
    for (int r = 0; r < 4; ++r) {
      const int orow = rt * 16 + l4 * 4 + r;
      const float v = acc[r] + bias;
      if (col < 512) ky[(size_t)orow * 512 + col] = (bf16_t)v;
      else           vy[(size_t)orow * 512 + (col - 512)] = (bf16_t)v;
    }
  }
}

// ------------------------------------------------------------
// store-flag inter-WG barrier: member m stores monotonic tag to its own
// padded flag; all WGs poll the 16 flags in parallel (lanes 0-15).
// Both sides relaxed AGENT scope (MALL) = one coherence point.
// ------------------------------------------------------------
__device__ __forceinline__ void flag_barrier(unsigned int* flags, int member,
                                             unsigned int target) {
  asm volatile("s_waitcnt vmcnt(0)" ::: "memory");  // my data stores are L2-acked
  __syncthreads();                                   // all waves' stores drained
  const int tid = threadIdx.x;
  if (tid == 0)
    __hip_atomic_store(flags + member * 16, target, __ATOMIC_RELAXED,
                       __HIP_MEMORY_SCOPE_AGENT);
  if (tid < 16) {
    const unsigned int* fp = flags + tid * 16;
    int guard = 0;
    while (__hip_atomic_load(fp, __ATOMIC_RELAXED, __HIP_MEMORY_SCOPE_AGENT) < target &&
           ++guard < (1 << 14))
      __builtin_amdgcn_s_sleep(1);
  }
  __syncthreads();
  asm volatile("" ::: "memory");                     // compiler fence for following loads
}

// ------------------------------------------------------------
// The recurrence. grid = 256 (batch = bid&15, member = bid>>4), block = 512.
// ------------------------------------------------------------
__global__ __launch_bounds__(512, 1) void recurrent_kernel(
    const bf16_t* __restrict__ WqkvH, const bf16_t* __restrict__ WqkvL,
    const bf16_t* __restrict__ WoH,   const bf16_t* __restrict__ WoL,
    const float* __restrict__ in_b, const float* __restrict__ ob,
    const float* __restrict__ ln_g, const float* __restrict__ ln_b,
    const float* __restrict__ mem_init,
    const bf16_t* __restrict__ ky, const bf16_t* __restrict__ vy,
    float* __restrict__ MS, bf16_t* __restrict__ scratch, unsigned int* __restrict__ ctr) {
  const int bid = blockIdx.x;
  const int batch = bid & 15;
  const int member = bid >> 4;
  const int tid = threadIdx.x;
  const int wave = tid >> 6;
  const int lane = tid & 63;
  const int l15 = lane & 15, l4 = lane >> 4;

  __shared__ __align__(16) float  Mst[8][520];       // state M (f32)
  __shared__ __align__(16) bf16_t AbfH[16][520];     // M hi (rows 8-15 zero)
  __shared__ __align__(16) bf16_t AbfL[16][520];     // M lo
  __shared__ __align__(16) bf16_t obfH[16][520];     // attn out hi
  __shared__ __align__(16) bf16_t obfL[16][520];     // attn out lo
  __shared__ __align__(16) bf16_t astH[8][16][40];   // softmax probs hi
  __shared__ __align__(16) bf16_t astL[8][16][40];   // softmax probs lo

  bf16_t* qb = scratch + (size_t)batch * 40960;      // [16][512] bf16, rows 8-15 = 0
  bf16_t* kb = qb + 8192;                            // [16][512] row 8 = ky_t, 9-15 = 0
  bf16_t* vT = kb + 8192;                            // [512][32] col 0-7 = vM, 8 = vy_t, 9-31 = 0
  float*  yb = (float*)(vT + 16384);                 // [8][512] f32
  unsigned int* flags = ctr + batch * 256;           // 16 members x 16 u32 (64B apart)

  // ---- preload weight B-fragments (hi+lo) into registers ----
  bf16x8_t wfh[16], wfl[16];
  {
    const bf16_t *wsh, *wsl;
    if (wave < 6) {
      wsh = WqkvH + (size_t)(member * 96 + wave * 16 + l15) * 512;
      wsl = WqkvL + (size_t)(member * 96 + wave * 16 + l15) * 512;
    } else {
      wsh = WoH + (size_t)(member * 32 + (wave - 6) * 16 + l15) * 512;
      wsl = WoL + (size_t)(member * 32 + (wave - 6) * 16 + l15) * 512;
    }
#pragma unroll
    for (int k = 0; k < 16; ++k) {
      wfh[k] = *(const bf16x8_t*)(wsh + k * 32 + l4 * 8);
      wfl[k] = *(const bf16x8_t*)(wsl + k * 32 + l4 * 8);
    }
  }
  const float biasA = (wave < 6) ? in_b[member * 96 + wave * 16 + l15]
                                 : ob[member * 32 + (wave - 6) * 16 + l15];
  float g8[8], b8[8];
#pragma unroll
  for (int i = 0; i < 8; ++i) { g8[i] = ln_g[lane * 8 + i]; b8[i] = ln_b[lane * 8 + i]; }

  // ---- ky/vy register prefetch (stager: member 15, waves 6-7) ----
  const bool stager = (member == 15 && wave >= 6);
  const int tt = tid - 384;                           // [0,128) on stager waves
  bf16x4_t kyr = {}, vyr = {};
  if (stager) {
    const bf16_t* kys = ky + (size_t)batch * 512 * 512;
    const bf16_t* vys = vy + (size_t)batch * 512 * 512;
    kyr = *(const bf16x4_t*)(kys + tt * 4);
    vyr = *(const bf16x4_t*)(vys + tt * 4);
  }

  // ---- init LDS ----
  {
    int c = tid;
    for (int r = 0; r < 8; ++r) {
      float v = mem_init[r * 512 + c];
      Mst[r][c] = v;
      bf16_t h = (bf16_t)v;
      AbfH[r][c] = h;
      AbfL[r][c] = (bf16_t)(v - (float)h);
    }
    for (int r = 8; r < 16; ++r) { AbfH[r][c] = (bf16_t)0.f; AbfL[r][c] = (bf16_t)0.f; }
    for (int i = tid; i < 8 * 16 * 40; i += 512) {
      ((bf16_t*)astH)[i] = (bf16_t)0.f;
      ((bf16_t*)astL)[i] = (bf16_t)0.f;
    }
  }
  __syncthreads();

  for (int t = 0; t < 512; ++t) {
    // ================= Phase A: QKV slices (split precision) =================
    if (wave < 6) {
      const int colbase = member * 96 + wave * 16;
      f32x4_t a0 = {0.f, 0.f, 0.f, 0.f};
      f32x4_t a1 = {0.f, 0.f, 0.f, 0.f};
      f32x4_t a2 = {0.f, 0.f, 0.f, 0.f};
#pragma unroll
      for (int k = 0; k < 16; ++k) {
        bf16x8_t ah = *(const bf16x8_t*)(&AbfH[l15][k * 32 + l4 * 8]);
        bf16x8_t al = *(const bf16x8_t*)(&AbfL[l15][k * 32 + l4 * 8]);
        a0 = MFMA16(ah, wfh[k], a0);
        a1 = MFMA16(al, wfh[k], a1);
        a2 = MFMA16(ah, wfl[k], a2);
      }
      const int col = colbase + l15;
#pragma unroll
      for (int r = 0; r < 4; ++r) {
        const int row = l4 * 4 + r;
        if (row < 8) {
          const float v = a0[r] + a1[r] + a2[r] + biasA;
          if (col < 512)       qb[row * 512 + col] = (bf16_t)v;
          else if (col < 1024) kb[row * 512 + (col - 512)] = (bf16_t)v;
          else                 vT[(col - 1024) * 32 + row] = (bf16_t)v;
        }
      }
    } else if (stager) {
      // store the prefetched y-token K/V row for this step
      const int c = tt * 4;
      *(bf16x4_t*)(kb + 8 * 512 + c) = kyr;
      vT[(c + 0) * 32 + 8] = vyr[0];
      vT[(c + 1) * 32 + 8] = vyr[1];
      vT[(c + 2) * 32 + 8] = vyr[2];
      vT[(c + 3) * 32 + 8] = vyr[3];
    }
    flag_barrier(flags, member, 2 * t + 1);

    // ================= Phase B: attention (redundant; wave = head) =================
    {
      const int h = wave;
      // issue all exchanged-data loads (sc0: bypass L1, hit shared L2)
      const bf16_t* qp = qb + l15 * 512 + h * 64 + l4 * 8;
      const bf16_t* kp = kb + l15 * 512 + h * 64 + l4 * 8;
      const bf16_t* vp = vT + (h * 64 + l15) * 32 + l4 * 8;
      bf16x8_t qa0 = ldg16(qp);
      bf16x8_t qa1 = ldg16(qp + 32);
      bf16x8_t kf0 = ldg16(kp);
      bf16x8_t kf1 = ldg16(kp + 32);
      bf16x8_t vv0 = ldg16(vp);
      bf16x8_t vv1 = ldg16(vp + 16 * 32);
      bf16x8_t vv2 = ldg16(vp + 32 * 32);
      bf16x8_t vv3 = ldg16(vp + 48 * 32);
      wait_vm0();

      // prefetch next step's ky/vy row (latency hidden under B/C/barrier)
      if (stager) {
        const int tn = (t + 1 < 512) ? t + 1 : 511;
        const bf16_t* kys = ky + ((size_t)batch * 512 + tn) * 512;
        const bf16_t* vys = vy + ((size_t)batch * 512 + tn) * 512;
        kyr = *(const bf16x4_t*)(kys + tt * 4);
        vyr = *(const bf16x4_t*)(vys + tt * 4);
      }

      f32x4_t s = {0.f, 0.f, 0.f, 0.f};
      s = MFMA16(qa0, kf0, s);
      s = MFMA16(qa1, kf1, s);

      float a4[4];
#pragma unroll
      for (int r = 0; r < 4; ++r) {
        float sv = (l15 <= 8) ? s[r] * 0.125f : -1e30f;
        float m = sv;
        m = fmaxf(m, __shfl_xor(m, 1));
        m = fmaxf(m, __shfl_xor(m, 2));
        m = fmaxf(m, __shfl_xor(m, 4));
        m = fmaxf(m, __shfl_xor(m, 8));
        float p = __expf(sv - m);
        float sum = p;
        sum += __shfl_xor(sum, 1);
        sum += __shfl_xor(sum, 2);
        sum += __shfl_xor(sum, 4);
        sum += __shfl_xor(sum, 8);
        a4[r] = p / sum;
      }
#pragma unroll
      for (int r = 0; r < 4; ++r) {
        const float p = a4[r];
        bf16_t ph = (bf16_t)p;
        astH[h][l4 * 4 + r][l15] = ph;
        astL[h][l4 * 4 + r][l15] = (bf16_t)(p - (float)ph);
      }
      __syncthreads();
      bf16x8_t aah = *(const bf16x8_t*)(&astH[h][l15][l4 * 8]);
      bf16x8_t aal = *(const bf16x8_t*)(&astL[h][l15][l4 * 8]);
      {
        f32x4_t z = {0.f, 0.f, 0.f, 0.f};
        f32x4_t o;
        o = MFMA16(aah, vv0, MFMA16(aal, vv0, z));
#pragma unroll
        for (int r = 0; r < 4; ++r) {
          float ov = o[r]; bf16_t oh = (bf16_t)ov;
          obfH[l4 * 4 + r][h * 64 + 0 * 16 + l15] = oh;
          obfL[l4 * 4 + r][h * 64 + 0 * 16 + l15] = (bf16_t)(ov - (float)oh);
        }
        o = MFMA16(aah, vv1, MFMA16(aal, vv1, z));
#pragma unroll
        for (int r = 0; r < 4; ++r) {
          float ov = o[r]; bf16_t oh = (bf16_t)ov;
          obfH[l4 * 4 + r][h * 64 + 1 * 16 + l15] = oh;
          obfL[l4 * 4 + r][h * 64 + 1 * 16 + l15] = (bf16_t)(ov - (float)oh);
        }
        o = MFMA16(aah, vv2, MFMA16(aal, vv2, z));
#pragma unroll
        for (int r = 0; r < 4; ++r) {
          float ov = o[r]; bf16_t oh = (bf16_t)ov;
          obfH[l4 * 4 + r][h * 64 + 2 * 16 + l15] = oh;
          obfL[l4 * 4 + r][h * 64 + 2 * 16 + l15] = (bf16_t)(ov - (float)oh);
        }
        o = MFMA16(aah, vv3, MFMA16(aal, vv3, z));
#pragma unroll
        for (int r = 0; r < 4; ++r) {
          float ov = o[r]; bf16_t oh = (bf16_t)ov;
          obfH[l4 * 4 + r][h * 64 + 3 * 16 + l15] = oh;
          obfL[l4 * 4 + r][h * 64 + 3 * 16 + l15] = (bf16_t)(ov - (float)oh);
        }
      }
    }
    __syncthreads();

    // ================= Phase C: out-proj slice + residual (split) =================
    if (wave >= 6) {
      const int colbase = member * 32 + (wave - 6) * 16;
      f32x4_t a0 = {0.f, 0.f, 0.f, 0.f};
      f32x4_t a1 = {0.f, 0.f, 0.f, 0.f};
      f32x4_t a2 = {0.f, 0.f, 0.f, 0.f};
#pragma unroll
      for (int k = 0; k < 16; ++k) {
        bf16x8_t oh = *(const bf16x8_t*)(&obfH[l15][k * 32 + l4 * 8]);
        bf16x8_t ol = *(const bf16x8_t*)(&obfL[l15][k * 32 + l4 * 8]);
        a0 = MFMA16(oh, wfh[k], a0);
        a1 = MFMA16(ol, wfh[k], a1);
        a2 = MFMA16(oh, wfl[k], a2);
      }
      const int col = colbase + l15;
#pragma unroll
      for (int r = 0; r < 4; ++r) {
        const int row = l4 * 4 + r;
        if (row < 8) yb[row * 512 + col] = a0[r] + a1[r] + a2[r] + biasA + Mst[row][col];
      }
    }
    flag_barrier(flags, member, 2 * t + 2);

    // ================= Phase D: LayerNorm (redundant; wave = row) =================
    {
      const int r = wave;
      const float* ysrc = yb + r * 512 + lane * 8;
      f32x4_t y0 = ldg16f(ysrc);
      f32x4_t y1 = ldg16f(ysrc + 4);
      wait_vm0();
      float yv[8];
      *(f32x4_t*)(yv)     = y0;
      *(f32x4_t*)(yv + 4) = y1;
      float s1 = 0.f, s2 = 0.f;
#pragma unroll
      for (int i = 0; i < 8; ++i) { s1 += yv[i]; s2 += yv[i] * yv[i]; }
#pragma unroll
      for (int m = 1; m < 64; m <<= 1) { s1 += __shfl_xor(s1, m); s2 += __shfl_xor(s2, m); }
      const float mu = s1 * (1.f / 512.f);
      const float var = s2 * (1.f / 512.f) - mu * mu;
      const float rinv = 1.f / sqrtf(var + 1e-5f);
      float mn[8];
      bf16x8_t mh, ml;
#pragma unroll
      for (int i = 0; i < 8; ++i) {
        mn[i] = (yv[i] - mu) * rinv * g8[i] + b8[i];
        mh[i] = (bf16_t)mn[i];
        ml[i] = (bf16_t)(mn[i] - (float)mh[i]);
      }
      *(f32x4_t*)(&Mst[r][lane * 8])     = *(f32x4_t*)(mn);
      *(f32x4_t*)(&Mst[r][lane * 8 + 4]) = *(f32x4_t*)(mn + 4);
      *(bf16x8_t*)(&AbfH[r][lane * 8]) = mh;
      *(bf16x8_t*)(&AbfL[r][lane * 8]) = ml;
    }
    __syncthreads();
    // summary (mean over the 8 memory rows), written by member 0 only
    {
      const int c = tid;
      float s = 0.f;
#pragma unroll
      for (int r = 0; r < 8; ++r) s += Mst[r][c];
      if (member == 0) MS[((size_t)batch * 512 + t) * 512 + c] = s * 0.125f;
    }
  }
}

// ------------------------------------------------------------
// out = relu(MS @ Wp^T + pb). grid (512, 8), block 256.
// ------------------------------------------------------------
__global__ __launch_bounds__(256) void fproj_kernel(
    const float* __restrict__ MS, const bf16_t* __restrict__ Wp,
    const float* __restrict__ pb, float* __restrict__ out) {
  const int rt = blockIdx.x, cg = blockIdx.y;
  const int wave = threadIdx.x >> 6, lane = threadIdx.x & 63;
  const int l15 = lane & 15, l4 = lane >> 4;

  const float* ms = MS + (size_t)(rt * 16 + l15) * 512;
  bf16x8_t afrag[16];
#pragma unroll
  for (int k = 0; k < 16; ++k) {
    f32x4_t lo = *(const f32x4_t*)(ms + k * 32 + l4 * 8);
    f32x4_t hi = *(const f32x4_t*)(ms + k * 32 + l4 * 8 + 4);
    bf16x8_t a;
#pragma unroll
    for (int j = 0; j < 4; ++j) { a[j] = (bf16_t)lo[j]; a[j + 4] = (bf16_t)hi[j]; }
    afrag[k] = a;
  }

#pragma unroll
  for (int dt = 0; dt < 4; ++dt) {
    const int col0 = cg * 256 + wave * 64 + dt * 16;
    const bf16_t* wsrc = Wp + (size_t)(col0 + l15) * 512;
    f32x4_t acc = {0.f, 0.f, 0.f, 0.f};
#pragma unroll
    for (int k = 0; k < 16; ++k)
      acc = MFMA16(afrag[k], *(const bf16x8_t*)(wsrc + k * 32 + l4 * 8), acc);
    const int col = col0 + l15;
    const float bias = pb[col];
#pragma unroll
    for (int r = 0; r < 4; ++r) {
      const size_t orow = (size_t)rt * 16 + l4 * 4 + r;
      out[orow * 2048 + col] = fmaxf(acc[r] + bias, 0.f);
    }
  }
}

// ------------------------------------------------------------
extern "C" void kernel_launch(void* const* d_in, const int* in_sizes, int n_in,
                              void* d_out, int out_size, void* d_ws, size_t ws_size,
                              hipStream_t stream) {
  (void)in_sizes; (void)n_in; (void)out_size; (void)ws_size;
  const int*   ids  = (const int*)d_in[0];
  const float* embt = (const float*)d_in[1];
  const float* mem0 = (const float*)d_in[2];
  const float* ipw  = (const float*)d_in[3];
  const float* ipb  = (const float*)d_in[4];
  const float* opw  = (const float*)d_in[5];
  const float* opb  = (const float*)d_in[6];
  const float* lng  = (const float*)d_in[7];
  const float* lnb  = (const float*)d_in[8];
  const float* pw   = (const float*)d_in[9];
  const float* pbv  = (const float*)d_in[10];
  float* out = (float*)d_out;
  char* ws = (char*)d_ws;

  bf16_t* WqkvH = (bf16_t*)(ws + WQKV_H_OFF);
  bf16_t* WqkvL = (bf16_t*)(ws + WQKV_L_OFF);
  bf16_t* WoH   = (bf16_t*)(ws + WO_H_OFF);
  bf16_t* WoL   = (bf16_t*)(ws + WO_L_OFF);
  bf16_t* Wp    = (bf16_t*)(ws + WP_OFF);
  bf16_t* ky    = (bf16_t*)(ws + KY_OFF);
  bf16_t* vy    = (bf16_t*)(ws + VY_OFF);
  float*  MS    = (float*)(ws + MS_OFF);
  bf16_t* scr   = (bf16_t*)(ws + SCR_OFF);
  unsigned int* ctr = (unsigned int*)(ws + CTR_OFF);

  // zero exchange buffers + barrier flags (ws is poisoned each call)
  hipMemsetAsync(ws + SCR_OFF, 0, SCR_BYTES + CTR_BYTES, stream);

  cvt_split_kernel<<<768, 256, 0, stream>>>(WqkvH, WqkvL, ipw, 1536 * 512);
  cvt_split_kernel<<<256, 256, 0, stream>>>(WoH, WoL, opw, 512 * 512);
  cvt_kernel<<<1024, 256, 0, stream>>>(Wp, pw, 2048 * 512);

  kyvy_kernel<<<dim3(512, 4), 256, 0, stream>>>(ids, embt, WqkvH, ipb, ky, vy);

  recurrent_kernel<<<256, 512, 0, stream>>>(WqkvH, WqkvL, WoH, WoL, ipb, opb,
                                            lng, lnb, mem0, ky, vy, MS, scr, ctr);

  fproj_kernel<<<dim3(512, 8), 256, 0, stream>>>(MS, Wp, pbv, out);
}